// Round 10
// baseline (181.290 us; speedup 1.0000x reference)
//
#include <hip/hip_runtime.h>
#include <hip/hip_bf16.h>
#include <math.h>

#define NNODES 8192
#define NEDGES 262144
#define INDIM  512
#define H1     256
#define H2     64

typedef __attribute__((ext_vector_type(8))) short bf16x8;
typedef __attribute__((ext_vector_type(4))) float f32x4;

static __device__ __forceinline__ float bf2f(unsigned short u) {
    return __uint_as_float((unsigned)u << 16);
}
static __device__ __forceinline__ unsigned short f2bf(float f) {
    __hip_bfloat16 h = __float2bfloat16(f);
    return *(unsigned short*)&h;
}

// ---------------- K1: prep (cast/transpose) + deg, fused via block ranges ----------
// deg's counters are zeroed by the preceding hipMemsetAsync (stream-ordered).

__global__ void prepdeg_kernel(const float* __restrict__ features, __hip_bfloat16* __restrict__ featb,
                               const float* __restrict__ W1, __hip_bfloat16* __restrict__ w1t,
                               const float* __restrict__ W2, __hip_bfloat16* __restrict__ w2t,
                               const int* __restrict__ src, const int* __restrict__ dst,
                               int* deg_out, int* deg_in) {
    int b = blockIdx.x;
    if (b < 4096) {
        int t = b * 256 + threadIdx.x;
        float4 v = ((const float4*)features)[t];
        ushort4 o;
        o.x = f2bf(v.x); o.y = f2bf(v.y); o.z = f2bf(v.z); o.w = f2bf(v.w);
        ((ushort4*)featb)[t] = o;
    } else if (b < 4608) {
        int t = (b - 4096) * 256 + threadIdx.x;   // t < INDIM*H1
        int k = t / H1, c = t % H1;
        w1t[(size_t)c * INDIM + k] = __float2bfloat16(W1[t]);
    } else if (b < 4672) {
        int t = (b - 4608) * 256 + threadIdx.x;   // t < H1*H2
        int k = t / H2, c = t % H2;
        w2t[(size_t)c * H1 + k] = __float2bfloat16(W2[t]);
    } else {
        int e = (b - 4672) * 256 + threadIdx.x;   // e < NEDGES
        atomicAdd(&deg_out[src[e]], 1);
        atomicAdd(&deg_in[dst[e]], 1);
    }
}

// ---------------- K2: scan + norms (single block) ----------------

__global__ __launch_bounds__(1024) void scannorm_kernel(const int* __restrict__ deg_in,
                                                        const int* __restrict__ deg_out,
                                                        int* __restrict__ row_start,
                                                        float* __restrict__ norm_out,
                                                        float* __restrict__ norm_in) {
    __shared__ int part[1024];
    int t = threadIdx.x;
    int v[8]; int s = 0;
#pragma unroll
    for (int u = 0; u < 8; u++) { v[u] = deg_in[t * 8 + u]; s += v[u]; }
    part[t] = s; __syncthreads();
    for (int off = 1; off < 1024; off <<= 1) {
        int x = part[t];
        if (t >= off) x += part[t - off];
        __syncthreads();
        part[t] = x;
        __syncthreads();
    }
    int run = part[t] - s;
#pragma unroll
    for (int u = 0; u < 8; u++) {
        int n = t * 8 + u;
        row_start[n] = run; run += v[u];
        norm_in[n]  = 1.0f / sqrtf(fmaxf((float)v[u], 1.0f));
        norm_out[n] = 1.0f / sqrtf(fmaxf((float)deg_out[n], 1.0f));
    }
    if (t == 1023) row_start[NNODES] = run;
}

// ---------------- gemm tile device fn (r6-validated 64x64 MFMA pattern) ----------

template<int K, int MT, int NT, int NOUT>
__device__ __forceinline__ void gemm_tile(const short* __restrict__ A, const short* __restrict__ BT,
                                          const float* __restrict__ scale, short* __restrict__ out,
                                          int bx, int by, int tid) {
    constexpr int AM = MT / 64;
    constexpr int BN = NT / 16;
    const int lane = tid & 63;
    const int wid  = tid >> 6;
    const int i0 = by * MT + wid * (MT / 4);
    const int j0 = bx * NT;
    const int fr = lane & 15;
    const int kg = lane >> 4;

    f32x4 acc[AM][BN] = {};
    for (int k0 = 0; k0 < K; k0 += 32) {
        bf16x8 a[AM], b[BN];
#pragma unroll
        for (int m = 0; m < AM; m++)
            a[m] = *(const bf16x8*)&A[(size_t)(i0 + m * 16 + fr) * K + k0 + kg * 8];
#pragma unroll
        for (int n = 0; n < BN; n++)
            b[n] = *(const bf16x8*)&BT[(size_t)(j0 + n * 16 + fr) * K + k0 + kg * 8];
#pragma unroll
        for (int m = 0; m < AM; m++)
#pragma unroll
            for (int n = 0; n < BN; n++)
                acc[m][n] = __builtin_amdgcn_mfma_f32_16x16x32_bf16(a[m], b[n], acc[m][n], 0, 0, 0);
    }

    const int col = lane & 15;
    const int rg4 = (lane >> 4) * 4;
#pragma unroll
    for (int m = 0; m < AM; m++)
#pragma unroll
        for (int r = 0; r < 4; r++) {
            int row = i0 + m * 16 + rg4 + r;
            float sc = scale[row];
#pragma unroll
            for (int n = 0; n < BN; n++)
                out[(size_t)row * NOUT + j0 + n * 16 + col] = f2bf(acc[m][n][r] * sc);
        }
}

// ---------------- K3: bucket (CSR scatter) + gemm1, fused via block ranges --------

__global__ __launch_bounds__(256) void bucketgemm_kernel(const int* __restrict__ src, const int* __restrict__ dst,
                                                         const int* __restrict__ row_start, int* cursor,
                                                         int* __restrict__ sorted_src,
                                                         const __hip_bfloat16* __restrict__ featb,
                                                         const __hip_bfloat16* __restrict__ w1t,
                                                         const float* __restrict__ norm_out,
                                                         __hip_bfloat16* __restrict__ xwb) {
    int b = blockIdx.x;
    if (b < 1024) {
        int e = b * 256 + threadIdx.x;
        int d = dst[e];
        int p = atomicAdd(&cursor[d], 1);
        sorted_src[row_start[d] + p] = src[e];
    } else {
        int g = b - 1024;                 // 512 gemm blocks: 128 (rows) x 4 (cols)
        gemm_tile<INDIM, 64, 64, H1>((const short*)featb, (const short*)w1t, norm_out,
                                     (short*)xwb, g & 3, g >> 2, threadIdx.x);
    }
}

// ---------------- K4: agg256 + gemm2 fused (16 nodes/block, MFMA phase 2) ---------
// 16 waves: wave w gathers node n0+w (identical access pattern to r9 agg256:
// coalesced 512 B rows, 8192 concurrent node-gathers). h row -> LDS as bf16
// (row stride 264 -> 2-way-free b128 reads). After one barrier, waves 0-3 do
// (h @ W2)*norm_out with the validated MFMA fragment pattern (w2t L2-resident).
// NO per-lane weight rows (r8 lesson).

__global__ __launch_bounds__(1024) void agg_gemm2_kernel(const int* __restrict__ row_start,
                                                         const int* __restrict__ sorted_src,
                                                         const __hip_bfloat16* __restrict__ msgb,
                                                         const float* __restrict__ norm_in,
                                                         const float* __restrict__ norm_out,
                                                         const float* __restrict__ b1,
                                                         const __hip_bfloat16* __restrict__ w2t,
                                                         __hip_bfloat16* __restrict__ hwb) {
    __shared__ short hs[16][H1 + 8];
    const ushort4* msg = (const ushort4*)msgb;
    const int wid  = threadIdx.x >> 6;
    const int lane = threadIdx.x & 63;
    const int n0 = blockIdx.x * 16;
    {
        int n = n0 + wid;
        int e0 = row_start[n], e1 = row_start[n + 1];
        float ax = 0.f, ay = 0.f, az = 0.f, aw = 0.f;
        int e = e0;
        for (; e + 1 < e1; e += 2) {
            int s0 = sorted_src[e], s1 = sorted_src[e + 1];
            ushort4 v0 = msg[(size_t)s0 * 64 + lane];
            ushort4 v1 = msg[(size_t)s1 * 64 + lane];
            ax += bf2f(v0.x) + bf2f(v1.x);
            ay += bf2f(v0.y) + bf2f(v1.y);
            az += bf2f(v0.z) + bf2f(v1.z);
            aw += bf2f(v0.w) + bf2f(v1.w);
        }
        if (e < e1) {
            ushort4 v0 = msg[(size_t)sorted_src[e] * 64 + lane];
            ax += bf2f(v0.x); ay += bf2f(v0.y); az += bf2f(v0.z); aw += bf2f(v0.w);
        }
        float ni = norm_in[n];
        float4 bb = ((const float4*)b1)[lane];
        ushort4 o;
        o.x = f2bf(fmaxf(ax * ni + bb.x, 0.f));
        o.y = f2bf(fmaxf(ay * ni + bb.y, 0.f));
        o.z = f2bf(fmaxf(az * ni + bb.z, 0.f));
        o.w = f2bf(fmaxf(aw * ni + bb.w, 0.f));
        *(ushort4*)&hs[wid][lane * 4] = o;
    }
    __syncthreads();
    if (wid < 4) {
        const short* BT = (const short*)w2t;
        const int fr = lane & 15;
        const int kg = lane >> 4;
        const int j0 = wid * 16;
        f32x4 acc = {};
#pragma unroll
        for (int k0 = 0; k0 < H1; k0 += 32) {
            bf16x8 a = *(const bf16x8*)&hs[fr][k0 + kg * 8];
            bf16x8 b = *(const bf16x8*)&BT[(size_t)(j0 + fr) * H1 + k0 + kg * 8];
            acc = __builtin_amdgcn_mfma_f32_16x16x32_bf16(a, b, acc, 0, 0, 0);
        }
        const int col = lane & 15;
        const int rg4 = (lane >> 4) * 4;
#pragma unroll
        for (int r = 0; r < 4; r++) {
            int nn = n0 + rg4 + r;
            hwb[(size_t)nn * H2 + j0 + col] = __float2bfloat16(acc[r] * norm_out[nn]);
        }
    }
}

// ---------------- K5: agg64 -> zb (bf16) ----------------

__global__ void agg64_kernel(const int* __restrict__ row_start, const int* __restrict__ sorted_src,
                             const __hip_bfloat16* __restrict__ msgb, const float* __restrict__ norm_in,
                             const float* __restrict__ bias, __hip_bfloat16* __restrict__ outb) {
    const unsigned* msg = (const unsigned*)msgb;
    int n = blockIdx.x;
    int lane = threadIdx.x;
    int half = lane >> 5, li = lane & 31;
    int e0 = row_start[n], e1 = row_start[n + 1];
    float ax = 0.f, ay = 0.f;
    for (int e = e0 + half; e < e1; e += 2) {
        unsigned u = msg[(size_t)sorted_src[e] * 32 + li];
        ax += bf2f((unsigned short)(u & 0xffff));
        ay += bf2f((unsigned short)(u >> 16));
    }
    ax += __shfl_xor(ax, 32);
    ay += __shfl_xor(ay, 32);
    if (half == 0) {
        float ni = norm_in[n];
        float z0 = ax * ni + bias[2 * li];
        float z1 = ay * ni + bias[2 * li + 1];
        unsigned o = (unsigned)f2bf(z0) | ((unsigned)f2bf(z1) << 16);
        ((unsigned*)outb)[(size_t)n * 32 + li] = o;
    }
}

// ---------------- K6: decoder = sigmoid(Zb @ Zb^T), bf16 MFMA + LDS transpose -----

#define LSTR 132

__global__ __launch_bounds__(256) void decoder_mfma_kernel(const __hip_bfloat16* __restrict__ zbf,
                                                           float* __restrict__ out) {
    __shared__ float lds[4][16 * LSTR];
    const short* zb = (const short*)zbf;
    const int lane = threadIdx.x & 63;
    const int wid  = threadIdx.x >> 6;
    const int i0 = blockIdx.y * 128 + wid * 32;
    const int j0 = blockIdx.x * 128;
    const int fr = lane & 15;
    const int kg = lane >> 4;

    f32x4 acc[2][8] = {};
#pragma unroll
    for (int ks = 0; ks < 2; ks++) {
        bf16x8 a[2], b[8];
#pragma unroll
        for (int m = 0; m < 2; m++)
            a[m] = *(const bf16x8*)&zb[(size_t)(i0 + m * 16 + fr) * H2 + ks * 32 + kg * 8];
#pragma unroll
        for (int n = 0; n < 8; n++)
            b[n] = *(const bf16x8*)&zb[(size_t)(j0 + n * 16 + fr) * H2 + ks * 32 + kg * 8];
#pragma unroll
        for (int m = 0; m < 2; m++)
#pragma unroll
            for (int n = 0; n < 8; n++)
                acc[m][n] = __builtin_amdgcn_mfma_f32_16x16x32_bf16(a[m], b[n], acc[m][n], 0, 0, 0);
    }

    float mx = 0.f;
#pragma unroll
    for (int m = 0; m < 2; m++)
#pragma unroll
        for (int n = 0; n < 8; n++)
#pragma unroll
            for (int r = 0; r < 4; r++)
                mx = fmaxf(mx, fabsf(acc[m][n][r]));
    const bool useExp = __any(mx > 1.0f);

    const int col = lane & 15;
    const int rg4 = (lane >> 4) * 4;
    float* L = lds[wid];
    const int rrow = (lane >> 5);
    const int rcol = (lane & 31) * 4;

#pragma unroll
    for (int m = 0; m < 2; m++) {
#pragma unroll
        for (int n = 0; n < 8; n++)
#pragma unroll
            for (int r = 0; r < 4; r++) {
                float x = acc[m][n][r];
                float s;
                if (useExp) {
                    s = 1.f / (1.f + __expf(-x));
                } else {
                    float u = x * x;
                    s = 0.5f + x * (0.25f + u * (-0.0208333333f + u * 0.0020833333f));
                }
                L[(rg4 + r) * LSTR + n * 16 + col] = s;
            }
#pragma unroll
        for (int i = 0; i < 8; i++) {
            int row = i * 2 + rrow;
            float4 v = *(float4*)&L[row * LSTR + rcol];
            *(float4*)&out[(size_t)(i0 + m * 16 + row) * NNODES + j0 + rcol] = v;
        }
    }
}

// ---------------- launcher (7 dispatches) ----------------

extern "C" void kernel_launch(void* const* d_in, const int* in_sizes, int n_in,
                              void* d_out, int out_size, void* d_ws, size_t ws_size,
                              hipStream_t stream) {
    const float* features = (const float*)d_in[0];
    const int*   src      = (const int*)d_in[1];
    const int*   dst      = (const int*)d_in[2];
    const float* W1       = (const float*)d_in[3];
    const float* b1       = (const float*)d_in[4];
    const float* W2       = (const float*)d_in[5];
    const float* b2       = (const float*)d_in[6];
    float* out = (float*)d_out;

    char* p = (char*)d_ws;
    auto alloc = [&](size_t bytes) -> void* {
        void* q = (void*)p;
        p += (bytes + 255) & ~(size_t)255;
        return q;
    };
    int*   deg_out_i  = (int*)alloc(NNODES * 4);   // contiguous trio (one memset)
    int*   deg_in_i   = (int*)alloc(NNODES * 4);
    int*   cursor     = (int*)alloc(NNODES * 4);
    int*   row_start  = (int*)alloc((NNODES + 1) * 4);
    float* norm_out   = (float*)alloc(NNODES * 4);
    float* norm_in    = (float*)alloc(NNODES * 4);
    int*   sorted_src = (int*)alloc(NEDGES * 4);
    __hip_bfloat16* featb = (__hip_bfloat16*)alloc((size_t)NNODES * INDIM * 2);
    __hip_bfloat16* w1t   = (__hip_bfloat16*)alloc((size_t)H1 * INDIM * 2);
    __hip_bfloat16* w2t   = (__hip_bfloat16*)alloc((size_t)H2 * H1 * 2);
    __hip_bfloat16* xwb   = (__hip_bfloat16*)alloc((size_t)NNODES * H1 * 2);
    __hip_bfloat16* hwb   = (__hip_bfloat16*)alloc((size_t)NNODES * H2 * 2);
    __hip_bfloat16* zb    = (__hip_bfloat16*)alloc((size_t)NNODES * H2 * 2);

    hipMemsetAsync(deg_out_i, 0, 3 * NNODES * 4, stream);                       // D1
    prepdeg_kernel<<<4672 + NEDGES / 256, 256, 0, stream>>>(                    // D2
        features, featb, W1, w1t, W2, w2t, src, dst, deg_out_i, deg_in_i);
    scannorm_kernel<<<1, 1024, 0, stream>>>(deg_in_i, deg_out_i,                // D3
                                            row_start, norm_out, norm_in);
    bucketgemm_kernel<<<1024 + 512, 256, 0, stream>>>(                          // D4
        src, dst, row_start, cursor, sorted_src, featb, w1t, norm_out, xwb);
    agg_gemm2_kernel<<<NNODES / 16, 1024, 0, stream>>>(                         // D5
        row_start, sorted_src, xwb, norm_in, norm_out, b1, w2t, hwb);
    agg64_kernel<<<NNODES, 64, 0, stream>>>(row_start, sorted_src, hwb,         // D6
                                            norm_in, b2, zb);
    decoder_mfma_kernel<<<dim3(NNODES / 128, NNODES / 128), 256, 0, stream>>>(  // D7
        zb, out);
}